// Round 1
// baseline (72.780 us; speedup 1.0000x reference)
//
#include <hip/hip_runtime.h>
#include <math.h>

// Gaussian KDE scatter for Voxelise.
//
// Key fact: exp(-d^2/200) underflows fp32 (even denormal) once d^2/200 > ~103.3,
// i.e. point-voxel distance > ~4.7 grid steps (step ~= 30.47). The reference
// computes exactly 0 for those pairs. So each point only touches an 11^3
// neighborhood (+-5 steps); everything outside is exactly zero in fp32.
// 2048 points x 1331 voxels = 2.7M candidate contributions (~900K non-zero)
// instead of 562M brute-force interactions.

#define NXv   65
#define NYZ   (65 * 65)
#define GTOT  (65 * 65 * 65)
#define RAD   5
#define WID   11            // 2*RAD + 1
#define WID3  (WID * WID * WID)

__global__ __launch_bounds__(128)
void kde_scatter(const float* __restrict__ pc,   // (npts, 3)
                 const float* __restrict__ tp,   // (3, 65, 65, 65)
                 float* __restrict__ out,        // (65,65,65), pre-zeroed
                 int npts) {
    __shared__ float sq[3][WID];   // per-axis squared distances
    __shared__ int   sbase[3];     // first voxel index per axis (i0 - RAD)

    const int p = blockIdx.x;
    if (p >= npts) return;
    const int tid = threadIdx.x;

    const float px = pc[3 * p + 0];
    const float py = pc[3 * p + 1];
    const float pz = pc[3 * p + 2];

    // Per-axis nearest-voxel index. Axis coordinates are read from
    // target_points itself (grid[0][i,0,0]=x_i stride NYZ; grid[1][0,j,0]=y_j
    // stride NXv; grid[2][0,0,k]=z_k stride 1) so they match JAX's linspace
    // output exactly.
    if (tid < 3) {
        const int   stride = (tid == 0) ? NYZ : ((tid == 1) ? NXv : 1);
        const float a0     = tp[(size_t)tid * GTOT];
        const float a1     = tp[(size_t)tid * GTOT + stride];
        const float step   = a1 - a0;
        const float c      = (tid == 0) ? px : ((tid == 1) ? py : pz);
        const int   i0     = (int)floorf((c - a0) / step + 0.5f);
        sbase[tid] = i0 - RAD;
    }
    __syncthreads();

    // 33 per-axis squared distances. Out-of-range -> huge s -> exp == 0.
    if (tid < 3 * WID) {
        const int axis = tid / WID;
        const int off  = tid - axis * WID;
        const int idx  = sbase[axis] + off;
        float s;
        if (idx < 0 || idx >= NXv) {
            s = 1e30f;
        } else {
            const int   stride = (axis == 0) ? NYZ : ((axis == 1) ? NXv : 1);
            const float g = tp[(size_t)axis * GTOT + (size_t)idx * stride];
            const float c = (axis == 0) ? px : ((axis == 1) ? py : pz);
            const float d = c - g;
            s = d * d;
        }
        sq[axis][off] = s;
    }
    __syncthreads();

    const int bx = sbase[0], by = sbase[1], bz = sbase[2];
    // 1/(2*pi*b^2), fp32 like the reference.
    const float inv_norm = 1.0f / (2.0f * 3.14159274101257324f * 100.0f);

    // 1331 voxels, 128 threads -> 11 iterations.
    for (int t = tid; t < WID3; t += 128) {
        const int di  = t / (WID * WID);
        const int rem = t - di * (WID * WID);
        const int dj  = rem / WID;
        const int dk  = rem - dj * WID;
        // exp of the summed squared distance — same rounding structure as the
        // reference's exp(-d2 / (2 b^2)).
        const float s = sq[0][di] + sq[1][dj] + sq[2][dk];
        const float w = expf(-s / 200.0f) * inv_norm;
        if (w != 0.0f) {   // also guards out-of-range voxels (s=1e30 -> w=0)
            const int lin = (bx + di) * NYZ + (by + dj) * NXv + (bz + dk);
            atomicAdd(&out[lin], w);
        }
    }
}

extern "C" void kernel_launch(void* const* d_in, const int* in_sizes, int n_in,
                              void* d_out, int out_size, void* d_ws, size_t ws_size,
                              hipStream_t stream) {
    const float* pc = (const float*)d_in[0];   // pointcloud (N, 3)
    const float* tp = (const float*)d_in[1];   // target_points (3, 65, 65, 65)
    float* out = (float*)d_out;                // (65, 65, 65) fp32

    const int npts = in_sizes[0] / 3;

    // d_out is poisoned to 0xAA before every timed launch — zero it.
    hipMemsetAsync(out, 0, (size_t)out_size * sizeof(float), stream);

    kde_scatter<<<npts, 128, 0, stream>>>(pc, tp, out, npts);
}